// Round 7
// baseline (161.547 us; speedup 1.0000x reference)
//
#include <hip/hip_runtime.h>

// YOLO loss, fp32. predictions: (batch,7,7,13), target: (batch,7,7,8), out: scalar.
// R6 post-mortem: three different persistent loop structures (R2/R4/R6) all
// plateau at 50.5us = 4.35 B/cyc/CU; per-iteration consume-reissue caps
// outstanding bytes/wave at ~6KB. R7: burst-and-die waves. Each wave issues
// its ENTIRE load set (21 x global_load_dwordx4 = 21KB) back-to-back, parks
// preds in a wave-private LDS slab, computes 256 cells, reduces, exits.
// Non-persistent 1568-block grid -> hardware wave churn provides pipelining.
// __launch_bounds__(256,3) (168 VGPR cap) prevents the R5 spill failure.

static constexpr int PRED_C = 13;   // 5*B + C
static constexpr int TGT_C  = 8;    // 1 + 4 + 3
static constexpr float L_NOOBJ = 0.5f;
static constexpr float L_COORD = 5.0f;
static constexpr float EPSI = 1e-6f;

static constexpr int WCELLS = 256;                  // cells per wave (4 tiles of 64)
static constexpr int SLAB4  = WCELLS * PRED_C / 4;  // 832 float4 = 13312 B/wave

__device__ __forceinline__ float iou_f(float ax, float ay, float aw, float ah,
                                       float bx, float by, float bw, float bh) {
    float ax1 = ax - aw * 0.5f, ax2 = ax + aw * 0.5f;
    float ay1 = ay - ah * 0.5f, ay2 = ay + ah * 0.5f;
    float bx1 = bx - bw * 0.5f, bx2 = bx + bw * 0.5f;
    float by1 = by - bh * 0.5f, by2 = by + bh * 0.5f;
    float iw = fmaxf(fminf(ax2, bx2) - fmaxf(ax1, bx1), 0.0f);
    float ih = fmaxf(fminf(ay2, by2) - fmaxf(ay1, by1), 0.0f);
    float inter = iw * ih;
    float uni = (ax2 - ax1) * (ay2 - ay1) + (bx2 - bx1) * (by2 - by1) - inter;
    return inter / (uni + EPSI);
}

// ta = target floats 0..3 (obj,x,y,w), tb = floats 4..7 (h, c0,c1,c2)
__device__ __forceinline__ float cell_loss(const float* __restrict__ p,
                                           float4 ta, float4 tb) {
    float m  = (ta.x == 1.0f) ? 1.0f : 0.0f;
    float tx = ta.y, ty = ta.z, tw = ta.w, th = tb.x;

    float b1c = p[0],  b1x = p[1],  b1y = p[2],  b1w = p[3], b1h = p[4];
    float b2c = p[5],  b2x = p[6],  b2y = p[7],  b2w = p[8], b2h = p[9];

    float i1 = iou_f(b1x, b1y, b1w, b1h, tx, ty, tw, th);
    float i2 = iou_f(b2x, b2y, b2w, b2h, tx, ty, tw, th);
    bool pick1 = i1 > i2;
    float iou = pick1 ? i1 : i2;
    float sc  = pick1 ? b1c : b2c;
    float sx  = pick1 ? b1x : b2x;
    float sy  = pick1 ? b1y : b2y;
    float sw  = pick1 ? b1w : b2w;
    float sh  = pick1 ? b1h : b2h;
    float uc  = pick1 ? b2c : b1c;

    float dx = sx - tx, dy = sy - ty;
    // sign(w)*sqrt(|w|): copysign matches jnp.sign semantics for finite inputs.
    float dw = copysignf(sqrtf(fabsf(sw)), sw) - sqrtf(tw);
    float dh = copysignf(sqrtf(fabsf(sh)), sh) - sqrtf(th);
    float l_coord = dx * dx + dy * dy + dw * dw + dh * dh;

    float doj = sc - iou;
    float d0 = p[10] - tb.y, d1 = p[11] - tb.z, d2 = p[12] - tb.w;
    float l_cls = d0 * d0 + d1 * d1 + d2 * d2;
    float l_noobj = m * uc * uc + (1.0f - m) * (b1c * b1c + b2c * b2c);

    return m * (L_COORD * l_coord + doj * doj + l_cls) + L_NOOBJ * l_noobj;
}

__global__ __launch_bounds__(256, 3) void yolo_main(const float* __restrict__ pred,
                                                    const float* __restrict__ tgt,
                                                    float* __restrict__ partial,
                                                    long long ncells) {
    __shared__ float4 sp4[4][SLAB4];   // wave-private 13312 B slab each (53.2 KB/block)
    __shared__ float wsum[4];

    const int t    = threadIdx.x;
    const int lane = t & 63;
    const int wave = t >> 6;
    float4* slab4 = sp4[wave];
    const float* slabf = (const float*)slab4;

    const long long gw    = (long long)blockIdx.x * 4 + wave;  // global wave id
    const long long cbase = gw * WCELLS;

    float acc = 0.0f;

    if (cbase + WCELLS <= ncells) {
        // ---- burst: issue ALL 21 loads back-to-back (21 KB in flight/wave) ----
        const float4* gp4 = (const float4*)pred + gw * SLAB4;
        float4 P0  = gp4[0 * 64 + lane];
        float4 P1  = gp4[1 * 64 + lane];
        float4 P2  = gp4[2 * 64 + lane];
        float4 P3  = gp4[3 * 64 + lane];
        float4 P4  = gp4[4 * 64 + lane];
        float4 P5  = gp4[5 * 64 + lane];
        float4 P6  = gp4[6 * 64 + lane];
        float4 P7  = gp4[7 * 64 + lane];
        float4 P8  = gp4[8 * 64 + lane];
        float4 P9  = gp4[9 * 64 + lane];
        float4 P10 = gp4[10 * 64 + lane];
        float4 P11 = gp4[11 * 64 + lane];
        float4 P12 = gp4[12 * 64 + lane];

        const float4* gt4 = (const float4*)tgt;
        float4 T[8];
#pragma unroll
        for (int k = 0; k < 4; ++k) {
            long long cell = cbase + 64 * k + lane;
            T[2 * k]     = gt4[cell * 2];
            T[2 * k + 1] = gt4[cell * 2 + 1];
        }

        // ---- park preds in LDS (precise vmcnt waits, oldest-first) ----
        slab4[0 * 64 + lane]  = P0;
        slab4[1 * 64 + lane]  = P1;
        slab4[2 * 64 + lane]  = P2;
        slab4[3 * 64 + lane]  = P3;
        slab4[4 * 64 + lane]  = P4;
        slab4[5 * 64 + lane]  = P5;
        slab4[6 * 64 + lane]  = P6;
        slab4[7 * 64 + lane]  = P7;
        slab4[8 * 64 + lane]  = P8;
        slab4[9 * 64 + lane]  = P9;
        slab4[10 * 64 + lane] = P10;
        slab4[11 * 64 + lane] = P11;
        slab4[12 * 64 + lane] = P12;

        // ---- compute 4 cells (stride-13 LDS reads: 2 lanes/bank = free) ----
        float pb[PRED_C];
#pragma unroll
        for (int k = 0; k < 4; ++k) {
#pragma unroll
            for (int i = 0; i < PRED_C; ++i)
                pb[i] = slabf[(64 * k + lane) * PRED_C + i];
            acc += cell_loss(pb, T[2 * k], T[2 * k + 1]);
        }
    } else {
        // generic tail (not hit at bench shape: ncells = 1568*1024 exact)
        for (int k = 0; k < 4; ++k) {
            long long cell = cbase + 64 * k + lane;
            if (cell < ncells) {
                float pb[PRED_C];
                for (int i = 0; i < PRED_C; ++i) pb[i] = pred[cell * PRED_C + i];
                const float4* gt4 = (const float4*)(tgt + cell * TGT_C);
                acc += cell_loss(pb, gt4[0], gt4[1]);
            }
        }
    }

    // wave64 shuffle reduction -> one partial per block (deterministic)
#pragma unroll
    for (int off = 32; off > 0; off >>= 1)
        acc += __shfl_down(acc, off, 64);
    if (lane == 0) wsum[wave] = acc;
    __syncthreads();
    if (t == 0) partial[blockIdx.x] = (wsum[0] + wsum[1]) + (wsum[2] + wsum[3]);
}

__global__ __launch_bounds__(256) void yolo_reduce(const float* __restrict__ partial,
                                                   float* __restrict__ out,
                                                   int nblocks, float inv_batch) {
    __shared__ float wsum[4];
    int t = threadIdx.x;
    float v = 0.0f;
    for (int i = t; i < nblocks; i += 256) v += partial[i];
#pragma unroll
    for (int off = 32; off > 0; off >>= 1)
        v += __shfl_down(v, off, 64);
    if ((t & 63) == 0) wsum[t >> 6] = v;
    __syncthreads();
    if (t == 0) out[0] = ((wsum[0] + wsum[1]) + (wsum[2] + wsum[3])) * inv_batch;
}

extern "C" void kernel_launch(void* const* d_in, const int* in_sizes, int n_in,
                              void* d_out, int out_size, void* d_ws, size_t ws_size,
                              hipStream_t stream) {
    const float* pred = (const float*)d_in[0];
    const float* tgt  = (const float*)d_in[1];
    float* out = (float*)d_out;
    float* partial = (float*)d_ws;                       // nblocks floats

    long long ncells = (long long)in_sizes[1] / TGT_C;   // batch*S*S = 1,605,632
    long long batch  = ncells / 49;                      // S=7
    float inv_batch  = 1.0f / (float)batch;

    long long cells_per_block = 4LL * WCELLS;            // 1024
    int nblocks = (int)((ncells + cells_per_block - 1) / cells_per_block);  // 1568

    yolo_main<<<nblocks, 256, 0, stream>>>(pred, tgt, partial, ncells);
    yolo_reduce<<<1, 256, 0, stream>>>(partial, out, nblocks, inv_batch);
}

// Round 8
// 150.836 us; speedup vs baseline: 1.0710x; 1.0710x over previous
//
#include <hip/hip_runtime.h>

// YOLO loss, fp32. predictions: (batch,7,7,13), target: (batch,7,7,8), out: scalar.
// R7 post-mortem: 4 orthogonal structures (R2/R4/R6/R7) all converge at
// 2.7-2.8 TB/s delivered read traffic; no CU-side resource is >15% busy ->
// chip-level streaming-read service wall. R8 = R7 + non-temporal load hints
// (final falsification: if L1/L2 allocation churn taxes the single-use read
// stream, nt bypasses it; if neutral, the plateau is structural -> roofline).

static constexpr int PRED_C = 13;   // 5*B + C
static constexpr int TGT_C  = 8;    // 1 + 4 + 3
static constexpr float L_NOOBJ = 0.5f;
static constexpr float L_COORD = 5.0f;
static constexpr float EPSI = 1e-6f;

static constexpr int WCELLS = 256;                  // cells per wave (4 tiles of 64)
static constexpr int SLAB4  = WCELLS * PRED_C / 4;  // 832 float4 = 13312 B/wave

typedef float v4f __attribute__((ext_vector_type(4)));

__device__ __forceinline__ float4 ntload4(const float4* p) {
    v4f v = __builtin_nontemporal_load((const v4f*)p);
    return make_float4(v.x, v.y, v.z, v.w);
}

__device__ __forceinline__ float iou_f(float ax, float ay, float aw, float ah,
                                       float bx, float by, float bw, float bh) {
    float ax1 = ax - aw * 0.5f, ax2 = ax + aw * 0.5f;
    float ay1 = ay - ah * 0.5f, ay2 = ay + ah * 0.5f;
    float bx1 = bx - bw * 0.5f, bx2 = bx + bw * 0.5f;
    float by1 = by - bh * 0.5f, by2 = by + bh * 0.5f;
    float iw = fmaxf(fminf(ax2, bx2) - fmaxf(ax1, bx1), 0.0f);
    float ih = fmaxf(fminf(ay2, by2) - fmaxf(ay1, by1), 0.0f);
    float inter = iw * ih;
    float uni = (ax2 - ax1) * (ay2 - ay1) + (bx2 - bx1) * (by2 - by1) - inter;
    return inter / (uni + EPSI);
}

// ta = target floats 0..3 (obj,x,y,w), tb = floats 4..7 (h, c0,c1,c2)
__device__ __forceinline__ float cell_loss(const float* __restrict__ p,
                                           float4 ta, float4 tb) {
    float m  = (ta.x == 1.0f) ? 1.0f : 0.0f;
    float tx = ta.y, ty = ta.z, tw = ta.w, th = tb.x;

    float b1c = p[0],  b1x = p[1],  b1y = p[2],  b1w = p[3], b1h = p[4];
    float b2c = p[5],  b2x = p[6],  b2y = p[7],  b2w = p[8], b2h = p[9];

    float i1 = iou_f(b1x, b1y, b1w, b1h, tx, ty, tw, th);
    float i2 = iou_f(b2x, b2y, b2w, b2h, tx, ty, tw, th);
    bool pick1 = i1 > i2;
    float iou = pick1 ? i1 : i2;
    float sc  = pick1 ? b1c : b2c;
    float sx  = pick1 ? b1x : b2x;
    float sy  = pick1 ? b1y : b2y;
    float sw  = pick1 ? b1w : b2w;
    float sh  = pick1 ? b1h : b2h;
    float uc  = pick1 ? b2c : b1c;

    float dx = sx - tx, dy = sy - ty;
    // sign(w)*sqrt(|w|): copysign matches jnp.sign semantics for finite inputs.
    float dw = copysignf(sqrtf(fabsf(sw)), sw) - sqrtf(tw);
    float dh = copysignf(sqrtf(fabsf(sh)), sh) - sqrtf(th);
    float l_coord = dx * dx + dy * dy + dw * dw + dh * dh;

    float doj = sc - iou;
    float d0 = p[10] - tb.y, d1 = p[11] - tb.z, d2 = p[12] - tb.w;
    float l_cls = d0 * d0 + d1 * d1 + d2 * d2;
    float l_noobj = m * uc * uc + (1.0f - m) * (b1c * b1c + b2c * b2c);

    return m * (L_COORD * l_coord + doj * doj + l_cls) + L_NOOBJ * l_noobj;
}

__global__ __launch_bounds__(256, 3) void yolo_main(const float* __restrict__ pred,
                                                    const float* __restrict__ tgt,
                                                    float* __restrict__ partial,
                                                    long long ncells) {
    __shared__ float4 sp4[4][SLAB4];   // wave-private 13312 B slab each (53.2 KB/block)
    __shared__ float wsum[4];

    const int t    = threadIdx.x;
    const int lane = t & 63;
    const int wave = t >> 6;
    float4* slab4 = sp4[wave];
    const float* slabf = (const float*)slab4;

    const long long gw    = (long long)blockIdx.x * 4 + wave;  // global wave id
    const long long cbase = gw * WCELLS;

    float acc = 0.0f;

    if (cbase + WCELLS <= ncells) {
        // ---- burst: issue ALL 21 loads back-to-back (21 KB in flight/wave),
        //      all non-temporal (single-use stream, skip cache allocation) ----
        const float4* gp4 = (const float4*)pred + gw * SLAB4;
        float4 P0  = ntload4(&gp4[0 * 64 + lane]);
        float4 P1  = ntload4(&gp4[1 * 64 + lane]);
        float4 P2  = ntload4(&gp4[2 * 64 + lane]);
        float4 P3  = ntload4(&gp4[3 * 64 + lane]);
        float4 P4  = ntload4(&gp4[4 * 64 + lane]);
        float4 P5  = ntload4(&gp4[5 * 64 + lane]);
        float4 P6  = ntload4(&gp4[6 * 64 + lane]);
        float4 P7  = ntload4(&gp4[7 * 64 + lane]);
        float4 P8  = ntload4(&gp4[8 * 64 + lane]);
        float4 P9  = ntload4(&gp4[9 * 64 + lane]);
        float4 P10 = ntload4(&gp4[10 * 64 + lane]);
        float4 P11 = ntload4(&gp4[11 * 64 + lane]);
        float4 P12 = ntload4(&gp4[12 * 64 + lane]);

        const float4* gt4 = (const float4*)tgt;
        float4 T[8];
#pragma unroll
        for (int k = 0; k < 4; ++k) {
            long long cell = cbase + 64 * k + lane;
            T[2 * k]     = ntload4(&gt4[cell * 2]);
            T[2 * k + 1] = ntload4(&gt4[cell * 2 + 1]);
        }

        // ---- park preds in LDS (precise vmcnt waits, oldest-first) ----
        slab4[0 * 64 + lane]  = P0;
        slab4[1 * 64 + lane]  = P1;
        slab4[2 * 64 + lane]  = P2;
        slab4[3 * 64 + lane]  = P3;
        slab4[4 * 64 + lane]  = P4;
        slab4[5 * 64 + lane]  = P5;
        slab4[6 * 64 + lane]  = P6;
        slab4[7 * 64 + lane]  = P7;
        slab4[8 * 64 + lane]  = P8;
        slab4[9 * 64 + lane]  = P9;
        slab4[10 * 64 + lane] = P10;
        slab4[11 * 64 + lane] = P11;
        slab4[12 * 64 + lane] = P12;

        // ---- compute 4 cells (stride-13 LDS reads: 2 lanes/bank = free) ----
        float pb[PRED_C];
#pragma unroll
        for (int k = 0; k < 4; ++k) {
#pragma unroll
            for (int i = 0; i < PRED_C; ++i)
                pb[i] = slabf[(64 * k + lane) * PRED_C + i];
            acc += cell_loss(pb, T[2 * k], T[2 * k + 1]);
        }
    } else {
        // generic tail (not hit at bench shape: ncells = 1568*1024 exact)
        for (int k = 0; k < 4; ++k) {
            long long cell = cbase + 64 * k + lane;
            if (cell < ncells) {
                float pb[PRED_C];
                for (int i = 0; i < PRED_C; ++i) pb[i] = pred[cell * PRED_C + i];
                const float4* gt4 = (const float4*)(tgt + cell * TGT_C);
                acc += cell_loss(pb, gt4[0], gt4[1]);
            }
        }
    }

    // wave64 shuffle reduction -> one partial per block (deterministic)
#pragma unroll
    for (int off = 32; off > 0; off >>= 1)
        acc += __shfl_down(acc, off, 64);
    if (lane == 0) wsum[wave] = acc;
    __syncthreads();
    if (t == 0) partial[blockIdx.x] = (wsum[0] + wsum[1]) + (wsum[2] + wsum[3]);
}

__global__ __launch_bounds__(256) void yolo_reduce(const float* __restrict__ partial,
                                                   float* __restrict__ out,
                                                   int nblocks, float inv_batch) {
    __shared__ float wsum[4];
    int t = threadIdx.x;
    float v = 0.0f;
    for (int i = t; i < nblocks; i += 256) v += partial[i];
#pragma unroll
    for (int off = 32; off > 0; off >>= 1)
        v += __shfl_down(v, off, 64);
    if ((t & 63) == 0) wsum[t >> 6] = v;
    __syncthreads();
    if (t == 0) out[0] = ((wsum[0] + wsum[1]) + (wsum[2] + wsum[3])) * inv_batch;
}

extern "C" void kernel_launch(void* const* d_in, const int* in_sizes, int n_in,
                              void* d_out, int out_size, void* d_ws, size_t ws_size,
                              hipStream_t stream) {
    const float* pred = (const float*)d_in[0];
    const float* tgt  = (const float*)d_in[1];
    float* out = (float*)d_out;
    float* partial = (float*)d_ws;                       // nblocks floats

    long long ncells = (long long)in_sizes[1] / TGT_C;   // batch*S*S = 1,605,632
    long long batch  = ncells / 49;                      // S=7
    float inv_batch  = 1.0f / (float)batch;

    long long cells_per_block = 4LL * WCELLS;            // 1024
    int nblocks = (int)((ncells + cells_per_block - 1) / cells_per_block);  // 1568

    yolo_main<<<nblocks, 256, 0, stream>>>(pred, tgt, partial, ncells);
    yolo_reduce<<<1, 256, 0, stream>>>(partial, out, nblocks, inv_batch);
}